// Round 1
// baseline (3155.448 us; speedup 1.0000x reference)
//
#include <hip/hip_runtime.h>

#define TOL 1e-6f
#define NITER 101
#define B 4
#define CCH 3
#define H 256
#define W 256
#define HW (H*W)            // 65536
#define NCHW (B*CCH*HW)     // 786432
#define NHW (B*HW)          // 262144

// workspace layout (float offsets)
#define WS_R   0
#define WS_P   (WS_R + NCHW)
#define WS_AP  (WS_P + NCHW)
#define WS_Q   (WS_AP + NCHW)
#define WS_SC  (WS_Q + NHW)
#define SC_COUNT 256
// sc[0] = guard (0 => inactive), sc[1+i] = crit_i (i=0..101),
// sc[103+j] = denom_j (j=0..100), sc[204] = dummy denom for init A-apply

__device__ __forceinline__ float block_reduce_sum(float v) {
    #pragma unroll
    for (int off = 32; off > 0; off >>= 1)
        v += __shfl_down(v, off, 64);
    __shared__ float red_[4];
    int lane = threadIdx.x & 63;
    int wid  = threadIdx.x >> 6;
    if (lane == 0) red_[wid] = v;
    __syncthreads();
    float s = 0.f;
    if (threadIdx.x == 0) {
        int nw = (blockDim.x + 63) >> 6;
        for (int i = 0; i < nw; ++i) s += red_[i];
    }
    return s; // valid on thread 0 only
}

// ---------------------------------------------------------------------------
// K1: fused  p = active_prev ? r + beta*p : p   (deferred from prev iter)
//            d = sum_c mask_c * p_c
//            t = P(d)   (3ch 3x3 conv, zero pad, cropped to grid)
//            q = PT(t)  (3x3 conv with flipped kernel, channel sum)
//            Ap = rho*p + mask*q ;  denom += p.Ap
// one block = one 32x32 spatial tile of one batch image
// ---------------------------------------------------------------------------
__launch_bounds__(256)
__global__ void k_fusedA(const float* __restrict__ mask,
                         const float* __restrict__ kern,   // 27 floats [3,1,3,3]
                         const float* __restrict__ rho_p,
                         const float* __restrict__ r_in,
                         const float* __restrict__ p_in,
                         float* __restrict__ p_out,
                         float* __restrict__ Ap_out,
                         const float* __restrict__ sc_prev, // crit_{j-1} (or guard)
                         const float* __restrict__ sc_cur,  // crit_j
                         float* __restrict__ denom_out)
{
    __shared__ float ksh[27];
    __shared__ float dext[36*36];
    __shared__ float tsh[3][34*34];
    __shared__ float pcore[3][32*32];
    __shared__ float mcore[3][32*32];

    const int tid = threadIdx.x;
    if (tid < 27) ksh[tid] = kern[tid];

    const int blk  = blockIdx.x;        // 0..255  (4 batches x 8x8 tiles)
    const int bi   = blk >> 6;
    const int tile = blk & 63;
    const int th0  = (tile >> 3) * 32;
    const int tw0  = (tile & 7) * 32;

    const float crit_prev = sc_prev[0];
    const float crit_cur  = sc_cur[0];
    const int   active_prev = crit_prev >= TOL;
    const float beta = crit_cur / (active_prev ? crit_prev : 1.0f);
    const float rho  = rho_p[0];

    // phase 1: p_new over extended 36x36 halo region; d = sum_c mask*p_new
    for (int e = tid; e < 36*36; e += 256) {
        const int eh = e / 36, ew = e % 36;
        const int gh = th0 + eh - 2, gw = tw0 + ew - 2;
        float dv = 0.f;
        const bool valid = ((unsigned)gh < H) && ((unsigned)gw < W);
        const bool core  = ((unsigned)(eh - 2) < 32) && ((unsigned)(ew - 2) < 32);
        if (valid) {
            const int base = (bi*CCH)*HW + gh*W + gw;
            #pragma unroll
            for (int c = 0; c < CCH; ++c) {
                const int idx = base + c*HW;
                float pv = p_in[idx];
                if (active_prev) pv = r_in[idx] + beta * pv;
                const float mv = mask[idx];
                dv += mv * pv;
                if (core) {
                    const int ci = (eh-2)*32 + (ew-2);
                    pcore[c][ci] = pv;
                    mcore[c][ci] = mv;
                }
            }
        }
        dext[e] = dv;
    }
    __syncthreads();

    // phase 2: t = P(d) on 34x34 (zero at out-of-grid positions => crop)
    for (int e = tid; e < 34*34; e += 256) {
        const int th = e / 34, tw = e % 34;
        const int gh = th0 + th - 1, gw = tw0 + tw - 1;
        float t0 = 0.f, t1 = 0.f, t2 = 0.f;
        if (((unsigned)gh < H) && ((unsigned)gw < W)) {
            #pragma unroll
            for (int i = 0; i < 3; ++i)
                #pragma unroll
                for (int j = 0; j < 3; ++j) {
                    const float dv = dext[(th+i)*36 + (tw+j)];
                    t0 += dv * ksh[0*9 + i*3 + j];
                    t1 += dv * ksh[1*9 + i*3 + j];
                    t2 += dv * ksh[2*9 + i*3 + j];
                }
        }
        tsh[0][e] = t0; tsh[1][e] = t1; tsh[2][e] = t2;
    }
    __syncthreads();

    // phase 3: q = PT(t) on core; Ap; denom partial
    float dsum = 0.f;
    for (int e = tid; e < 32*32; e += 256) {
        const int h = e >> 5, w = e & 31;
        float q = 0.f;
        #pragma unroll
        for (int o = 0; o < 3; ++o)
            #pragma unroll
            for (int i = 0; i < 3; ++i)
                #pragma unroll
                for (int j = 0; j < 3; ++j)
                    q += tsh[o][(h+i)*34 + (w+j)] * ksh[o*9 + (2-i)*3 + (2-j)];

        const int gbase = (bi*CCH)*HW + (th0+h)*W + (tw0+w);
        #pragma unroll
        for (int c = 0; c < CCH; ++c) {
            const int idx = gbase + c*HW;
            const float pv = pcore[c][e];
            const float ap = rho * pv + mcore[c][e] * q;
            Ap_out[idx] = ap;
            if (active_prev) p_out[idx] = pv;
            dsum += pv * ap;
        }
    }
    const float tot = block_reduce_sum(dsum);
    if (tid == 0) atomicAdd(denom_out, tot);
}

// ---------------------------------------------------------------------------
// K2: alpha = crit/denom (masked); x += a*p; r -= a*Ap; crit_next += r.r
// ---------------------------------------------------------------------------
__launch_bounds__(256)
__global__ void k_update(const float* __restrict__ Ap,
                         const float* __restrict__ p,
                         float* __restrict__ x,
                         float* __restrict__ r,
                         const float* __restrict__ crit_cur,
                         const float* __restrict__ denom_p,
                         float* __restrict__ crit_next)
{
    const float crit = crit_cur[0];
    const int active = crit >= TOL;
    const float alpha = crit / (active ? denom_p[0] : 1.0f);
    float acc = 0.f;
    for (int i = blockIdx.x * blockDim.x + threadIdx.x; i < NCHW;
         i += gridDim.x * blockDim.x) {
        float rv = r[i];
        if (active) {
            x[i] += alpha * p[i];
            rv -= alpha * Ap[i];
            r[i] = rv;
        }
        acc += rv * rv;
    }
    const float tot = block_reduce_sum(acc);
    if (threadIdx.x == 0) atomicAdd(crit_next, tot);
}

// ---------------------------------------------------------------------------
// Init kernels (run once; naive is fine)
// ---------------------------------------------------------------------------
__global__ void k_convP(const float* __restrict__ y,
                        const float* __restrict__ kern,
                        float* __restrict__ t)
{
    const int idx = blockIdx.x * 256 + threadIdx.x;
    if (idx >= NCHW) return;
    const int w  = idx & (W-1);
    const int h  = (idx >> 8) & (H-1);
    const int co = idx >> 16;       // b*3 + o
    const int o  = co % 3;
    const int b  = co / 3;
    const float* yb = y + b*HW;
    float acc = 0.f;
    #pragma unroll
    for (int i = 0; i < 3; ++i) {
        const int gh = h + i - 1;
        if ((unsigned)gh >= H) continue;
        #pragma unroll
        for (int j = 0; j < 3; ++j) {
            const int gw = w + j - 1;
            if ((unsigned)gw >= W) continue;
            acc += yb[gh*W + gw] * kern[o*9 + i*3 + j];
        }
    }
    t[idx] = acc;
}

__global__ void k_convPT(const float* __restrict__ t,
                         const float* __restrict__ kern,
                         float* __restrict__ q)
{
    const int idx = blockIdx.x * 256 + threadIdx.x;
    if (idx >= NHW) return;
    const int w = idx & (W-1);
    const int h = (idx >> 8) & (H-1);
    const int b = idx >> 16;
    const float* tb = t + b*CCH*HW;
    float acc = 0.f;
    #pragma unroll
    for (int i = 0; i < 3; ++i) {
        const int gh = h + i - 1;
        if ((unsigned)gh >= H) continue;
        #pragma unroll
        for (int j = 0; j < 3; ++j) {
            const int gw = w + j - 1;
            if ((unsigned)gw >= W) continue;
            #pragma unroll
            for (int o = 0; o < 3; ++o)
                acc += tb[o*HW + gh*W + gw] * kern[o*9 + (2-i)*3 + (2-j)];
        }
    }
    q[idx] = acc;
}

__global__ void k_initB(const float* __restrict__ mask,
                        const float* __restrict__ q,
                        const float* __restrict__ z,
                        const float* __restrict__ bet,
                        const float* __restrict__ rho_p,
                        float* __restrict__ x)
{
    const int idx = blockIdx.x * 256 + threadIdx.x;
    if (idx >= NCHW) return;
    const int hw = idx & (HW-1);
    const int b  = idx / (CCH*HW);
    x[idx] = mask[idx] * q[b*HW + hw] + rho_p[0] * (z[idx] - bet[idx]);
}

__launch_bounds__(256)
__global__ void k_initR(const float* __restrict__ x,
                        const float* __restrict__ Ap,
                        float* __restrict__ r,
                        float* __restrict__ p,
                        float* __restrict__ crit0)
{
    float acc = 0.f;
    for (int i = blockIdx.x * blockDim.x + threadIdx.x; i < NCHW;
         i += gridDim.x * blockDim.x) {
        const float rv = x[i] - Ap[i];
        r[i] = rv;
        p[i] = rv;
        acc += rv * rv;
    }
    const float tot = block_reduce_sum(acc);
    if (threadIdx.x == 0) atomicAdd(crit0, tot);
}

extern "C" void kernel_launch(void* const* d_in, const int* in_sizes, int n_in,
                              void* d_out, int out_size, void* d_ws, size_t ws_size,
                              hipStream_t stream)
{
    const float* mask = (const float*)d_in[0];
    const float* y    = (const float*)d_in[1];
    const float* z    = (const float*)d_in[2];
    const float* bet  = (const float*)d_in[3];
    const float* rho  = (const float*)d_in[4];
    const float* kern = (const float*)d_in[5];

    float* x  = (float*)d_out;
    float* ws = (float*)d_ws;
    float* r  = ws + WS_R;
    float* p  = ws + WS_P;
    float* Ap = ws + WS_AP;
    float* q  = ws + WS_Q;
    float* sc = ws + WS_SC;

    // zero the scalar slots (ws is poisoned 0xAA before every timed call)
    hipMemsetAsync(sc, 0, SC_COUNT * sizeof(float), stream);

    // b = mask * PT(P(y)) + rho*(z - beta)  -> x0 = b
    k_convP <<<NCHW/256, 256, 0, stream>>>(y, kern, Ap);
    k_convPT<<<NHW/256,  256, 0, stream>>>(Ap, kern, q);
    k_initB <<<NCHW/256, 256, 0, stream>>>(mask, q, z, bet, rho, x);

    // Ap = A(x0)   (guard slot => inactive => p not modified/written)
    k_fusedA<<<256, 256, 0, stream>>>(mask, kern, rho, x, x, p, Ap,
                                      sc + 0, sc + 1, sc + 204);
    // r0 = b - A(x0); p0 = r0; crit0
    k_initR<<<512, 256, 0, stream>>>(x, Ap, r, p, sc + 1);

    for (int j = 0; j < NITER; ++j) {
        // deferred p-update uses active_{j-1} = crit[j-1] >= TOL (guard for j=0)
        k_fusedA<<<256, 256, 0, stream>>>(mask, kern, rho, r, p, p, Ap,
                                          sc + j, sc + 1 + j, sc + 103 + j);
        k_update<<<512, 256, 0, stream>>>(Ap, p, x, r,
                                          sc + 1 + j, sc + 103 + j, sc + 2 + j);
    }
}